// Round 8
// baseline (639.120 us; speedup 1.0000x reference)
//
#include <hip/hip_runtime.h>
#include <hip/hip_bf16.h>
#include <math.h>

#define NN 100000
#define NE 1600000

#define NBUCK 8
#define BSZ (NN / NBUCK)       // 12500
#define CHUNKS 32
#define CH_E (NE / CHUNKS)     // 50000

#define SCAN_BLK 256
#define NB_SCAN ((NN + SCAN_BLK - 1) / SCAN_BLK)   // 391

typedef float f32x4 __attribute__((ext_vector_type(4)));
typedef short s16x8 __attribute__((ext_vector_type(8)));
typedef unsigned short u16x4 __attribute__((ext_vector_type(4)));

static inline int grid_for(long total, int block, long cap = 16384) {
    long b = (total + block - 1) / block;
    if (b > cap) b = cap;
    if (b < 1) b = 1;
    return (int)b;
}

__device__ __forceinline__ unsigned short f2b(float f) {
    __hip_bfloat16 h = __float2bfloat16(f);   // round-to-nearest
    return __builtin_bit_cast(unsigned short, h);
}
__device__ __forceinline__ float b2f(unsigned short u) {
    unsigned int x = ((unsigned int)u) << 16;
    return __builtin_bit_cast(float, x);
}

// ================= graph preprocessing (no global atomics) =================

// Block (g = bid&7, c = bid>>3): LDS histograms of src/dst within bucket g over
// edge chunk c; write plain partial counts to scratch (no global atomics).
__global__ __launch_bounds__(256) void partial_hist_kernel(
    const int* __restrict__ src, const int* __restrict__ dst,
    int* __restrict__ scratch_src, int* __restrict__ scratch_dst)
{
    __shared__ int hs[BSZ];
    __shared__ int hd[BSZ];
    int g = blockIdx.x & 7, c = blockIdx.x >> 3;
    int lo = g * BSZ;
    for (int i = threadIdx.x; i < BSZ; i += 256) { hs[i] = 0; hd[i] = 0; }
    __syncthreads();
    int e0 = c * CH_E;
    for (int e = e0 + threadIdx.x; e < e0 + CH_E; e += 256) {
        unsigned si = (unsigned)(src[e] - lo);
        unsigned di = (unsigned)(dst[e] - lo);
        if (si < BSZ) atomicAdd(&hs[si], 1);
        if (di < BSZ) atomicAdd(&hd[di], 1);
    }
    __syncthreads();
    int* os = scratch_src + ((size_t)g * CHUNKS + c) * BSZ;
    int* od = scratch_dst + ((size_t)g * CHUNKS + c) * BSZ;
    for (int i = threadIdx.x; i < BSZ; i += 256) { os[i] = hs[i]; od[i] = hd[i]; }
}

// Sum 32 chunk-partials per node -> norms (fused) + cnt_dst for the scan.
__global__ void reduce_hist_kernel(const int* __restrict__ scratch_src,
                                   const int* __restrict__ scratch_dst,
                                   float* __restrict__ ns, float* __restrict__ nd,
                                   int* __restrict__ cnt_dst) {
    int n = blockIdx.x * blockDim.x + threadIdx.x;
    if (n >= NN) return;
    int g = n / BSZ, i = n - g * BSZ;
    const int* ps = scratch_src + (size_t)g * CHUNKS * BSZ + i;
    const int* pd = scratch_dst + (size_t)g * CHUNKS * BSZ + i;
    int cs = 0, cd = 0;
#pragma unroll
    for (int c = 0; c < CHUNKS; ++c) { cs += ps[(size_t)c * BSZ]; cd += pd[(size_t)c * BSZ]; }
    ns[n] = rsqrtf(fmaxf((float)cs, 1.0f));
    nd[n] = rsqrtf(fmaxf((float)cd, 1.0f));
    cnt_dst[n] = cd;
}

__global__ void block_sum_kernel(const int* __restrict__ cnt, int* __restrict__ partials) {
    __shared__ int sm[SCAN_BLK];
    int i = blockIdx.x * SCAN_BLK + threadIdx.x;
    sm[threadIdx.x] = (i < NN) ? cnt[i] : 0;
    __syncthreads();
    for (int s = SCAN_BLK / 2; s > 0; s >>= 1) {
        if (threadIdx.x < s) sm[threadIdx.x] += sm[threadIdx.x + s];
        __syncthreads();
    }
    if (threadIdx.x == 0) partials[blockIdx.x] = sm[0];
}

__global__ void scan_partials_kernel(int* __restrict__ p) {
    __shared__ int sm[512];
    int tid = threadIdx.x;
    int v = (tid < NB_SCAN) ? p[tid] : 0;
    sm[tid] = v;
    __syncthreads();
    for (int off = 1; off < 512; off <<= 1) {
        int t = (tid >= off) ? sm[tid - off] : 0;
        __syncthreads();
        sm[tid] += t;
        __syncthreads();
    }
    if (tid < NB_SCAN) p[tid] = sm[tid] - v;   // exclusive
}

__global__ void block_scan_kernel(const int* __restrict__ cnt, const int* __restrict__ partials,
                                  int* __restrict__ row_ptr) {
    __shared__ int sm[SCAN_BLK];
    int i = blockIdx.x * SCAN_BLK + threadIdx.x;
    int v = (i < NN) ? cnt[i] : 0;
    sm[threadIdx.x] = v;
    __syncthreads();
    for (int off = 1; off < SCAN_BLK; off <<= 1) {
        int t = (threadIdx.x >= off) ? sm[threadIdx.x - off] : 0;
        __syncthreads();
        sm[threadIdx.x] += t;
        __syncthreads();
    }
    if (i < NN) {
        int excl = partials[blockIdx.x] + sm[threadIdx.x] - v;
        row_ptr[i] = excl;
        if (i == NN - 1) row_ptr[NN] = excl + v;
    }
}

// Turn dst chunk-partials into per-(node,chunk) start offsets (in place).
__global__ void chunk_offs_kernel(int* __restrict__ scratch_dst, const int* __restrict__ row_ptr) {
    int n = blockIdx.x * blockDim.x + threadIdx.x;
    if (n >= NN) return;
    int g = n / BSZ, i = n - g * BSZ;
    int* pd = scratch_dst + (size_t)g * CHUNKS * BSZ + i;
    int base = row_ptr[n];
#pragma unroll
    for (int c = 0; c < CHUNKS; ++c) {
        int t = pd[(size_t)c * BSZ];
        pd[(size_t)c * BSZ] = base;
        base += t;
    }
}

// Atomic-free-in-global CSR fill: block (g,c) loads its bucket/chunk offsets to
// LDS, places edges via LDS atomics, writes col_src to disjoint regions.
__global__ __launch_bounds__(256) void fill_chunked_kernel(
    const int* __restrict__ src, const int* __restrict__ dst,
    const int* __restrict__ scratch_dst, int* __restrict__ col_src)
{
    __shared__ int off[BSZ];
    int g = blockIdx.x & 7, c = blockIdx.x >> 3;
    int lo = g * BSZ;
    const int* pd = scratch_dst + ((size_t)g * CHUNKS + c) * BSZ;
    for (int i = threadIdx.x; i < BSZ; i += 256) off[i] = pd[i];
    __syncthreads();
    int e0 = c * CH_E;
    for (int e = e0 + threadIdx.x; e < e0 + CH_E; e += 256) {
        unsigned di = (unsigned)(dst[e] - lo);
        if (di < BSZ) {
            int p = atomicAdd(&off[di], 1);
            col_src[p] = src[e];
        }
    }
}

// ================= bf16 prep =================

__global__ void f32_to_bf16_kernel(const float* __restrict__ in, unsigned short* __restrict__ out,
                                   int n4) {
    int t = blockIdx.x * blockDim.x + threadIdx.x;
    if (t >= n4) return;
    f32x4 v = reinterpret_cast<const f32x4*>(in)[t];
    u16x4 o;
#pragma unroll
    for (int j = 0; j < 4; ++j) o[j] = f2b(v[j]);
    reinterpret_cast<u16x4*>(out)[t] = o;
}

// W [K_REAL][N_REAL] f32 -> fragment-packed bf16 (zero-padded).
// Wf[frag*512 + lane*8 + j] = W[kt*32 + (lane>>4)*8 + j][nt*16 + (lane&15)]
template <int K_REAL, int N_REAL, int NTILES>
__global__ void repack_kernel(const float* __restrict__ W, unsigned short* __restrict__ Wf,
                              int total) {
    int t = blockIdx.x * blockDim.x + threadIdx.x;
    if (t >= total) return;
    int j = t & 7, lane = (t >> 3) & 63, frag = t >> 9;
    int kt = frag / NTILES, nt = frag - kt * NTILES;
    int k = kt * 32 + (lane >> 4) * 8 + j;
    int n = nt * 16 + (lane & 15);
    float v = (k < K_REAL && n < N_REAL) ? W[(size_t)k * N_REAL + n] : 0.0f;
    Wf[t] = f2b(v);
}

__global__ void padbias_kernel(const float* __restrict__ b, float* __restrict__ bp,
                               int nreal, int npad) {
    int t = blockIdx.x * blockDim.x + threadIdx.x;
    if (t < npad) bp[t] = (t < nreal) ? b[t] : 0.0f;
}

// ================= MFMA GEMM =================
// EPI 1: bf16 out[row*(NTILES*16) + col] = elu(acc * rowscale[row] + bias[col])
// EPI 2: bf16 out[row*N_REAL + col]     = acc * rowscale[row]   (col < N_REAL only)
template <int K_STEPS, int NTILES, int N_REAL, int EPI, int K_PAD>
__global__ __launch_bounds__(256) void gemm_kernel(
    const unsigned short* __restrict__ Abf, const unsigned short* __restrict__ Wf,
    const float* __restrict__ rowscale, const float* __restrict__ bias,
    void* __restrict__ outv)
{
    int wave = blockIdx.x * (blockDim.x >> 6) + (threadIdx.x >> 6);
    int row0 = wave << 4;
    if (row0 >= NN) return;
    int lane = threadIdx.x & 63;
    int r = lane & 15, half = lane >> 4;

    f32x4 acc[NTILES];
#pragma unroll
    for (int nt = 0; nt < NTILES; ++nt) acc[nt] = (f32x4)(0.0f);

    const unsigned short* arow = Abf + (size_t)(row0 + r) * K_PAD + half * 8;
#pragma unroll
    for (int kt = 0; kt < K_STEPS; ++kt) {
        s16x8 a = *reinterpret_cast<const s16x8*>(arow + kt * 32);
#pragma unroll
        for (int nt = 0; nt < NTILES; ++nt) {
            s16x8 b = *reinterpret_cast<const s16x8*>(
                Wf + (((kt * NTILES + nt) << 9) | (lane << 3)));
            acc[nt] = __builtin_amdgcn_mfma_f32_16x16x32_bf16(a, b, acc[nt], 0, 0, 0);
        }
    }

    int colbase = lane & 15;
    float rs[4];
#pragma unroll
    for (int j = 0; j < 4; ++j) rs[j] = rowscale[row0 + half * 4 + j];

    if (EPI == 2) {
        unsigned short* out = (unsigned short*)outv;
#pragma unroll
        for (int nt = 0; nt < NTILES; ++nt) {
            int col = nt * 16 + colbase;
            if (col < N_REAL) {
#pragma unroll
                for (int j = 0; j < 4; ++j) {
                    int row = row0 + half * 4 + j;
                    out[(size_t)row * N_REAL + col] = f2b(acc[nt][j] * rs[j]);
                }
            }
        }
    } else {
        unsigned short* out = (unsigned short*)outv;
        const int NOUT = NTILES * 16;
#pragma unroll
        for (int nt = 0; nt < NTILES; ++nt) {
            int col = nt * 16 + colbase;
            float bv = bias[col];
#pragma unroll
            for (int j = 0; j < 4; ++j) {
                int row = row0 + half * 4 + j;
                float v = acc[nt][j] * rs[j] + bv;
                v = (v > 0.0f) ? v : expm1f(v);
                out[(size_t)row * NOUT + col] = f2b(v);
            }
        }
    }
}

// ================= gathers (vectorized) =================

// gather1: y1 bf16 [NN][100] -> h1s bf16 [NN][100];  h1s = elu(sum*nd + b1) * ns
__global__ void gather1_kernel(const unsigned short* __restrict__ y, const int* __restrict__ row_ptr,
                               const int* __restrict__ col_src, const float* __restrict__ ns,
                               const float* __restrict__ nd, const float* __restrict__ bias,
                               unsigned short* __restrict__ out) {
    unsigned t = blockIdx.x * blockDim.x + threadIdx.x;
    if (t >= NN * 25u) return;
    unsigned n = t / 25u, g = t - n * 25u;
    int start = row_ptr[n], end = row_ptr[n + 1];
    f32x4 acc = (f32x4)(0.0f);
    for (int i = start; i < end; ++i) {
        int s = col_src[i];
        u16x4 v = *reinterpret_cast<const u16x4*>(y + (size_t)s * 100 + g * 4);
#pragma unroll
        for (int j = 0; j < 4; ++j) acc[j] += b2f(v[j]);
    }
    f32x4 b4 = *reinterpret_cast<const f32x4*>(bias + g * 4);
    float ndv = nd[n], nsv = ns[n];
    u16x4 o;
#pragma unroll
    for (int j = 0; j < 4; ++j) {
        float v = acc[j] * ndv + b4[j];
        v = (v > 0.0f) ? v : expm1f(v);
        o[j] = f2b(v * nsv);
    }
    *reinterpret_cast<u16x4*>(out + (size_t)n * 100 + g * 4) = o;
}

// gather2: h1s bf16 [NN][100] -> agg2b bf16 [NN][128] (raw sums, cols 0..99)
__global__ void gather2_kernel(const unsigned short* __restrict__ y, const int* __restrict__ row_ptr,
                               const int* __restrict__ col_src, unsigned short* __restrict__ out) {
    unsigned t = blockIdx.x * blockDim.x + threadIdx.x;
    if (t >= NN * 25u) return;
    unsigned n = t / 25u, g = t - n * 25u;
    int start = row_ptr[n], end = row_ptr[n + 1];
    f32x4 acc = (f32x4)(0.0f);
    for (int i = start; i < end; ++i) {
        int s = col_src[i];
        u16x4 v = *reinterpret_cast<const u16x4*>(y + (size_t)s * 100 + g * 4);
#pragma unroll
        for (int j = 0; j < 4; ++j) acc[j] += b2f(v[j]);
    }
    u16x4 o;
#pragma unroll
    for (int j = 0; j < 4; ++j) o[j] = f2b(acc[j]);
    *reinterpret_cast<u16x4*>(out + (size_t)n * 128 + g * 4) = o;
}

// gather3: y3 bf16 [NN][64] -> out f32 [NN][64];  out = sigmoid(sum*nd + b3)
__global__ void gather3_kernel(const unsigned short* __restrict__ y, const int* __restrict__ row_ptr,
                               const int* __restrict__ col_src, const float* __restrict__ nd,
                               const float* __restrict__ bias, float* __restrict__ out) {
    unsigned t = blockIdx.x * blockDim.x + threadIdx.x;
    if (t >= NN * 16u) return;
    unsigned n = t >> 4, g = t & 15u;
    int start = row_ptr[n], end = row_ptr[n + 1];
    f32x4 acc = (f32x4)(0.0f);
    for (int i = start; i < end; ++i) {
        int s = col_src[i];
        u16x4 v = *reinterpret_cast<const u16x4*>(y + (size_t)s * 64 + g * 4);
#pragma unroll
        for (int j = 0; j < 4; ++j) acc[j] += b2f(v[j]);
    }
    f32x4 b4 = *reinterpret_cast<const f32x4*>(bias + g * 4);
    float ndv = nd[n];
    f32x4 o;
#pragma unroll
    for (int j = 0; j < 4; ++j) {
        float v = acc[j] * ndv + b4[j];
        o[j] = 1.0f / (1.0f + expf(-v));
    }
    *reinterpret_cast<f32x4*>(out + (size_t)n * 64 + g * 4) = o;
}

// ================= launch =================

extern "C" void kernel_launch(void* const* d_in, const int* in_sizes, int n_in,
                              void* d_out, int out_size, void* d_ws, size_t ws_size,
                              hipStream_t stream) {
    const float* x    = (const float*)d_in[0];
    const int*   esrc = (const int*)d_in[1];
    const int*   edst = (const int*)d_in[2];
    const float* W1   = (const float*)d_in[3];
    const float* b1   = (const float*)d_in[4];
    const float* W2   = (const float*)d_in[5];
    const float* b2   = (const float*)d_in[6];
    const float* W3   = (const float*)d_in[7];
    const float* b3   = (const float*)d_in[8];
    float* out = (float*)d_out;

    // ---- workspace carving (256B-aligned regions) ----
    char* base = (char*)d_ws;
    size_t off = 0;
    auto alloc = [&](size_t bytes) -> void* {
        void* p = base + off;
        off += (bytes + 255) & ~(size_t)255;
        return p;
    };
    // region1: xb (bf16 [NN][128]) -> agg2b (bf16 [NN][128]) -> y3 (bf16 [NN][64])
    void* region1 = alloc((size_t)NN * 128 * 2);
    // region2: scratch_src+scratch_dst (int [2][8][32][12500], preprocessing only)
    //          -> y1 (bf16 [NN][100]) -> h2b (bf16 [NN][224])
    void* region2 = alloc((size_t)NN * 224 * 2);
    // region3: h1s (bf16 [NN][100])
    void* region3 = alloc((size_t)NN * 100 * 2);
    float* ns       = (float*)alloc(NN * 4);
    float* nd       = (float*)alloc(NN * 4);
    int*   cnt_dst  = (int*)alloc(NN * 4);
    int*   row_ptr  = (int*)alloc((NN + 1) * 4);
    int*   col_src  = (int*)alloc((size_t)NE * 4);
    int*   partials = (int*)alloc(512 * 4);
    unsigned short* W1f = (unsigned short*)alloc(4 * 7 * 512 * 2);    // K=128,N=112
    unsigned short* W2f = (unsigned short*)alloc(4 * 14 * 512 * 2);   // K=128,N=224
    unsigned short* W3f = (unsigned short*)alloc(7 * 4 * 512 * 2);    // K=224,N=64
    float* b2p = (float*)alloc(224 * 4);

    unsigned short* xb    = (unsigned short*)region1;
    unsigned short* agg2b = (unsigned short*)region1;
    unsigned short* y3    = (unsigned short*)region1;
    int* scratch_src      = (int*)region2;                          // 12.8 MB
    int* scratch_dst      = scratch_src + (size_t)NBUCK * CHUNKS * BSZ;  // 12.8 MB
    unsigned short* y1    = (unsigned short*)region2;
    unsigned short* h2b   = (unsigned short*)region2;
    unsigned short* h1s   = (unsigned short*)region3;

    const int BLK = 256;
    const int GEMM_GRID = (NN / 16 + 3) / 4;   // 6250 waves / 4 per block = 1563

    // ---- graph preprocessing (no global atomics) ----
    partial_hist_kernel<<<NBUCK * CHUNKS, 256, 0, stream>>>(esrc, edst, scratch_src, scratch_dst);
    reduce_hist_kernel<<<grid_for(NN, BLK), BLK, 0, stream>>>(scratch_src, scratch_dst,
                                                              ns, nd, cnt_dst);
    block_sum_kernel<<<NB_SCAN, SCAN_BLK, 0, stream>>>(cnt_dst, partials);
    scan_partials_kernel<<<1, 512, 0, stream>>>(partials);
    block_scan_kernel<<<NB_SCAN, SCAN_BLK, 0, stream>>>(cnt_dst, partials, row_ptr);
    chunk_offs_kernel<<<grid_for(NN, BLK), BLK, 0, stream>>>(scratch_dst, row_ptr);
    fill_chunked_kernel<<<NBUCK * CHUNKS, 256, 0, stream>>>(esrc, edst, scratch_dst, col_src);

    // ---- bf16 prep ----
    f32_to_bf16_kernel<<<grid_for((long)NN * 128 / 4, BLK, 1 << 30), BLK, 0, stream>>>(
        x, xb, NN * 128 / 4);
    repack_kernel<128, 100, 7><<<grid_for(28 * 512, BLK), BLK, 0, stream>>>(W1, W1f, 28 * 512);
    repack_kernel<100, 200, 14><<<grid_for(56 * 512, BLK), BLK, 0, stream>>>(W2, W2f, 56 * 512);
    repack_kernel<200, 64, 4><<<grid_for(28 * 512, BLK), BLK, 0, stream>>>(W3, W3f, 28 * 512);
    padbias_kernel<<<1, 256, 0, stream>>>(b2, b2p, 200, 224);

    // ---- L1: y1 = (x @ W1) * ns  (bf16 [NN][100]) ----  (y1 overwrites scratch; OK, fill done)
    gemm_kernel<4, 7, 100, 2, 128><<<GEMM_GRID, BLK, 0, stream>>>(xb, W1f, ns, nullptr, y1);
    // h1s = elu(gather(y1)*nd + b1) * ns  (bf16 [NN][100])
    gather1_kernel<<<grid_for((long)NN * 25, BLK, 1 << 30), BLK, 0, stream>>>(
        y1, row_ptr, col_src, ns, nd, b1, h1s);

    // ---- L2: agg2 = gather(h1s)  (bf16 [NN][128], zero-padded) ----
    hipMemsetAsync(agg2b, 0, (size_t)NN * 128 * 2, stream);
    gather2_kernel<<<grid_for((long)NN * 25, BLK, 1 << 30), BLK, 0, stream>>>(
        h1s, row_ptr, col_src, agg2b);
    // h2 = elu((agg2 @ W2)*nd + b2)  (bf16 [NN][224], pads auto-zero)
    gemm_kernel<4, 14, 200, 1, 128><<<GEMM_GRID, BLK, 0, stream>>>(agg2b, W2f, nd, b2p, h2b);

    // ---- L3: y3 = (h2 @ W3) * ns  (bf16 [NN][64]) ----
    gemm_kernel<7, 4, 64, 2, 224><<<GEMM_GRID, BLK, 0, stream>>>(h2b, W3f, ns, nullptr, y3);
    // out = sigmoid(gather(y3)*nd + b3)
    gather3_kernel<<<grid_for((long)NN * 16, BLK, 1 << 30), BLK, 0, stream>>>(
        y3, row_ptr, col_src, nd, b3, out);
}

// Round 9
// 523.965 us; speedup vs baseline: 1.2198x; 1.2198x over previous
//
#include <hip/hip_runtime.h>
#include <hip/hip_bf16.h>
#include <math.h>

#define NN 100000
#define NE 1600000

#define NBUCK 16
#define BSZ (NN / NBUCK)       // 6250
#define CHUNKS 64
#define CH_E (NE / CHUNKS)     // 25000

#define SCAN_BLK 256
#define NB_SCAN ((NN + SCAN_BLK - 1) / SCAN_BLK)   // 391

typedef float f32x4 __attribute__((ext_vector_type(4)));
typedef short s16x8 __attribute__((ext_vector_type(8)));
typedef unsigned short u16x4 __attribute__((ext_vector_type(4)));
typedef int i32x4 __attribute__((ext_vector_type(4)));

static inline int grid_for(long total, int block, long cap = 16384) {
    long b = (total + block - 1) / block;
    if (b > cap) b = cap;
    if (b < 1) b = 1;
    return (int)b;
}

__device__ __forceinline__ unsigned short f2b(float f) {
    __hip_bfloat16 h = __float2bfloat16(f);   // round-to-nearest
    return __builtin_bit_cast(unsigned short, h);
}
__device__ __forceinline__ float b2f(unsigned short u) {
    unsigned int x = ((unsigned int)u) << 16;
    return __builtin_bit_cast(float, x);
}

// ================= graph preprocessing (no global atomics) =================

// Block (g = bid&15, c = bid>>4): LDS histograms of src/dst within bucket g over
// edge chunk c; write plain partial counts to scratch (no global atomics).
__global__ __launch_bounds__(256) void partial_hist_kernel(
    const int* __restrict__ src, const int* __restrict__ dst,
    int* __restrict__ scratch_src, int* __restrict__ scratch_dst)
{
    __shared__ int hs[BSZ];
    __shared__ int hd[BSZ];
    int g = blockIdx.x & 15, c = blockIdx.x >> 4;
    int lo = g * BSZ;
    for (int i = threadIdx.x; i < BSZ; i += 256) { hs[i] = 0; hd[i] = 0; }
    __syncthreads();
    const i32x4* src4 = reinterpret_cast<const i32x4*>(src + c * CH_E);
    const i32x4* dst4 = reinterpret_cast<const i32x4*>(dst + c * CH_E);
    for (int i = threadIdx.x; i < CH_E / 4; i += 256) {
        i32x4 s4 = src4[i];
        i32x4 d4 = dst4[i];
#pragma unroll
        for (int j = 0; j < 4; ++j) {
            unsigned si = (unsigned)(s4[j] - lo);
            unsigned di = (unsigned)(d4[j] - lo);
            if (si < BSZ) atomicAdd(&hs[si], 1);
            if (di < BSZ) atomicAdd(&hd[di], 1);
        }
    }
    __syncthreads();
    int* os = scratch_src + ((size_t)g * CHUNKS + c) * BSZ;
    int* od = scratch_dst + ((size_t)g * CHUNKS + c) * BSZ;
    for (int i = threadIdx.x; i < BSZ; i += 256) { os[i] = hs[i]; od[i] = hd[i]; }
}

// Sum chunk-partials per node -> norms (fused) + cnt_dst for the scan.
__global__ void reduce_hist_kernel(const int* __restrict__ scratch_src,
                                   const int* __restrict__ scratch_dst,
                                   float* __restrict__ ns, float* __restrict__ nd,
                                   int* __restrict__ cnt_dst) {
    int n = blockIdx.x * blockDim.x + threadIdx.x;
    if (n >= NN) return;
    int g = n / BSZ, i = n - g * BSZ;
    const int* ps = scratch_src + (size_t)g * CHUNKS * BSZ + i;
    const int* pd = scratch_dst + (size_t)g * CHUNKS * BSZ + i;
    int cs = 0, cd = 0;
#pragma unroll 8
    for (int c = 0; c < CHUNKS; ++c) { cs += ps[(size_t)c * BSZ]; cd += pd[(size_t)c * BSZ]; }
    ns[n] = rsqrtf(fmaxf((float)cs, 1.0f));
    nd[n] = rsqrtf(fmaxf((float)cd, 1.0f));
    cnt_dst[n] = cd;
}

__global__ void block_sum_kernel(const int* __restrict__ cnt, int* __restrict__ partials) {
    __shared__ int sm[SCAN_BLK];
    int i = blockIdx.x * SCAN_BLK + threadIdx.x;
    sm[threadIdx.x] = (i < NN) ? cnt[i] : 0;
    __syncthreads();
    for (int s = SCAN_BLK / 2; s > 0; s >>= 1) {
        if (threadIdx.x < s) sm[threadIdx.x] += sm[threadIdx.x + s];
        __syncthreads();
    }
    if (threadIdx.x == 0) partials[blockIdx.x] = sm[0];
}

__global__ void scan_partials_kernel(int* __restrict__ p) {
    __shared__ int sm[512];
    int tid = threadIdx.x;
    int v = (tid < NB_SCAN) ? p[tid] : 0;
    sm[tid] = v;
    __syncthreads();
    for (int off = 1; off < 512; off <<= 1) {
        int t = (tid >= off) ? sm[tid - off] : 0;
        __syncthreads();
        sm[tid] += t;
        __syncthreads();
    }
    if (tid < NB_SCAN) p[tid] = sm[tid] - v;   // exclusive
}

__global__ void block_scan_kernel(const int* __restrict__ cnt, const int* __restrict__ partials,
                                  int* __restrict__ row_ptr) {
    __shared__ int sm[SCAN_BLK];
    int i = blockIdx.x * SCAN_BLK + threadIdx.x;
    int v = (i < NN) ? cnt[i] : 0;
    sm[threadIdx.x] = v;
    __syncthreads();
    for (int off = 1; off < SCAN_BLK; off <<= 1) {
        int t = (threadIdx.x >= off) ? sm[threadIdx.x - off] : 0;
        __syncthreads();
        sm[threadIdx.x] += t;
        __syncthreads();
    }
    if (i < NN) {
        int excl = partials[blockIdx.x] + sm[threadIdx.x] - v;
        row_ptr[i] = excl;
        if (i == NN - 1) row_ptr[NN] = excl + v;
    }
}

// Turn dst chunk-partials into per-(node,chunk) start offsets (in place).
__global__ void chunk_offs_kernel(int* __restrict__ scratch_dst, const int* __restrict__ row_ptr) {
    int n = blockIdx.x * blockDim.x + threadIdx.x;
    if (n >= NN) return;
    int g = n / BSZ, i = n - g * BSZ;
    int* pd = scratch_dst + (size_t)g * CHUNKS * BSZ + i;
    int base = row_ptr[n];
#pragma unroll 8
    for (int c = 0; c < CHUNKS; ++c) {
        int t = pd[(size_t)c * BSZ];
        pd[(size_t)c * BSZ] = base;
        base += t;
    }
}

// Atomic-free-in-global CSR fill: block (g,c) loads its bucket/chunk offsets to
// LDS, places edges via LDS atomics, writes col_src to disjoint regions.
__global__ __launch_bounds__(256) void fill_chunked_kernel(
    const int* __restrict__ src, const int* __restrict__ dst,
    const int* __restrict__ scratch_dst, int* __restrict__ col_src)
{
    __shared__ int off[BSZ];
    int g = blockIdx.x & 15, c = blockIdx.x >> 4;
    int lo = g * BSZ;
    const int* pd = scratch_dst + ((size_t)g * CHUNKS + c) * BSZ;
    for (int i = threadIdx.x; i < BSZ; i += 256) off[i] = pd[i];
    __syncthreads();
    const i32x4* src4 = reinterpret_cast<const i32x4*>(src + c * CH_E);
    const i32x4* dst4 = reinterpret_cast<const i32x4*>(dst + c * CH_E);
    for (int i = threadIdx.x; i < CH_E / 4; i += 256) {
        i32x4 s4 = src4[i];
        i32x4 d4 = dst4[i];
#pragma unroll
        for (int j = 0; j < 4; ++j) {
            unsigned di = (unsigned)(d4[j] - lo);
            if (di < BSZ) {
                int p = atomicAdd(&off[di], 1);
                col_src[p] = s4[j];
            }
        }
    }
}

// ================= bf16 prep =================

__global__ void f32_to_bf16_kernel(const float* __restrict__ in, unsigned short* __restrict__ out,
                                   int n4) {
    int t = blockIdx.x * blockDim.x + threadIdx.x;
    if (t >= n4) return;
    f32x4 v = reinterpret_cast<const f32x4*>(in)[t];
    u16x4 o;
#pragma unroll
    for (int j = 0; j < 4; ++j) o[j] = f2b(v[j]);
    reinterpret_cast<u16x4*>(out)[t] = o;
}

// W [K_REAL][N_REAL] f32 -> fragment-packed bf16 (zero-padded).
// Wf[frag*512 + lane*8 + j] = W[kt*32 + (lane>>4)*8 + j][nt*16 + (lane&15)]
template <int K_REAL, int N_REAL, int NTILES>
__global__ void repack_kernel(const float* __restrict__ W, unsigned short* __restrict__ Wf,
                              int total) {
    int t = blockIdx.x * blockDim.x + threadIdx.x;
    if (t >= total) return;
    int j = t & 7, lane = (t >> 3) & 63, frag = t >> 9;
    int kt = frag / NTILES, nt = frag - kt * NTILES;
    int k = kt * 32 + (lane >> 4) * 8 + j;
    int n = nt * 16 + (lane & 15);
    float v = (k < K_REAL && n < N_REAL) ? W[(size_t)k * N_REAL + n] : 0.0f;
    Wf[t] = f2b(v);
}

__global__ void padbias_kernel(const float* __restrict__ b, float* __restrict__ bp,
                               int nreal, int npad) {
    int t = blockIdx.x * blockDim.x + threadIdx.x;
    if (t < npad) bp[t] = (t < nreal) ? b[t] : 0.0f;
}

// ================= MFMA GEMM =================
// EPI 1: bf16 out[row*(NTILES*16) + col] = elu(acc * rowscale[row] + bias[col])
// EPI 2: bf16 out[row*N_REAL + col]     = acc * rowscale[row]   (col < N_REAL only)
template <int K_STEPS, int NTILES, int N_REAL, int EPI, int K_PAD>
__global__ __launch_bounds__(256) void gemm_kernel(
    const unsigned short* __restrict__ Abf, const unsigned short* __restrict__ Wf,
    const float* __restrict__ rowscale, const float* __restrict__ bias,
    void* __restrict__ outv)
{
    int wave = blockIdx.x * (blockDim.x >> 6) + (threadIdx.x >> 6);
    int row0 = wave << 4;
    if (row0 >= NN) return;
    int lane = threadIdx.x & 63;
    int r = lane & 15, half = lane >> 4;

    f32x4 acc[NTILES];
#pragma unroll
    for (int nt = 0; nt < NTILES; ++nt) acc[nt] = (f32x4)(0.0f);

    const unsigned short* arow = Abf + (size_t)(row0 + r) * K_PAD + half * 8;
#pragma unroll
    for (int kt = 0; kt < K_STEPS; ++kt) {
        s16x8 a = *reinterpret_cast<const s16x8*>(arow + kt * 32);
#pragma unroll
        for (int nt = 0; nt < NTILES; ++nt) {
            s16x8 b = *reinterpret_cast<const s16x8*>(
                Wf + (((kt * NTILES + nt) << 9) | (lane << 3)));
            acc[nt] = __builtin_amdgcn_mfma_f32_16x16x32_bf16(a, b, acc[nt], 0, 0, 0);
        }
    }

    int colbase = lane & 15;
    float rs[4];
#pragma unroll
    for (int j = 0; j < 4; ++j) rs[j] = rowscale[row0 + half * 4 + j];

    if (EPI == 2) {
        unsigned short* out = (unsigned short*)outv;
#pragma unroll
        for (int nt = 0; nt < NTILES; ++nt) {
            int col = nt * 16 + colbase;
            if (col < N_REAL) {
#pragma unroll
                for (int j = 0; j < 4; ++j) {
                    int row = row0 + half * 4 + j;
                    out[(size_t)row * N_REAL + col] = f2b(acc[nt][j] * rs[j]);
                }
            }
        }
    } else {
        unsigned short* out = (unsigned short*)outv;
        const int NOUT = NTILES * 16;
#pragma unroll
        for (int nt = 0; nt < NTILES; ++nt) {
            int col = nt * 16 + colbase;
            float bv = bias[col];
#pragma unroll
            for (int j = 0; j < 4; ++j) {
                int row = row0 + half * 4 + j;
                float v = acc[nt][j] * rs[j] + bv;
                v = (v > 0.0f) ? v : expm1f(v);
                out[(size_t)row * NOUT + col] = f2b(v);
            }
        }
    }
}

// ================= gathers (vectorized) =================

// gather1: y1 bf16 [NN][100] -> h1s bf16 [NN][100];  h1s = elu(sum*nd + b1) * ns
__global__ void gather1_kernel(const unsigned short* __restrict__ y, const int* __restrict__ row_ptr,
                               const int* __restrict__ col_src, const float* __restrict__ ns,
                               const float* __restrict__ nd, const float* __restrict__ bias,
                               unsigned short* __restrict__ out) {
    unsigned t = blockIdx.x * blockDim.x + threadIdx.x;
    if (t >= NN * 25u) return;
    unsigned n = t / 25u, g = t - n * 25u;
    int start = row_ptr[n], end = row_ptr[n + 1];
    f32x4 acc = (f32x4)(0.0f);
    for (int i = start; i < end; ++i) {
        int s = col_src[i];
        u16x4 v = *reinterpret_cast<const u16x4*>(y + (size_t)s * 100 + g * 4);
#pragma unroll
        for (int j = 0; j < 4; ++j) acc[j] += b2f(v[j]);
    }
    f32x4 b4 = *reinterpret_cast<const f32x4*>(bias + g * 4);
    float ndv = nd[n], nsv = ns[n];
    u16x4 o;
#pragma unroll
    for (int j = 0; j < 4; ++j) {
        float v = acc[j] * ndv + b4[j];
        v = (v > 0.0f) ? v : expm1f(v);
        o[j] = f2b(v * nsv);
    }
    *reinterpret_cast<u16x4*>(out + (size_t)n * 100 + g * 4) = o;
}

// gather2: h1s bf16 [NN][100] -> agg2b bf16 [NN][128] (raw sums, cols 0..99)
__global__ void gather2_kernel(const unsigned short* __restrict__ y, const int* __restrict__ row_ptr,
                               const int* __restrict__ col_src, unsigned short* __restrict__ out) {
    unsigned t = blockIdx.x * blockDim.x + threadIdx.x;
    if (t >= NN * 25u) return;
    unsigned n = t / 25u, g = t - n * 25u;
    int start = row_ptr[n], end = row_ptr[n + 1];
    f32x4 acc = (f32x4)(0.0f);
    for (int i = start; i < end; ++i) {
        int s = col_src[i];
        u16x4 v = *reinterpret_cast<const u16x4*>(y + (size_t)s * 100 + g * 4);
#pragma unroll
        for (int j = 0; j < 4; ++j) acc[j] += b2f(v[j]);
    }
    u16x4 o;
#pragma unroll
    for (int j = 0; j < 4; ++j) o[j] = f2b(acc[j]);
    *reinterpret_cast<u16x4*>(out + (size_t)n * 128 + g * 4) = o;
}

// gather3: y3 bf16 [NN][64] -> out f32 [NN][64];  out = sigmoid(sum*nd + b3)
__global__ void gather3_kernel(const unsigned short* __restrict__ y, const int* __restrict__ row_ptr,
                               const int* __restrict__ col_src, const float* __restrict__ nd,
                               const float* __restrict__ bias, float* __restrict__ out) {
    unsigned t = blockIdx.x * blockDim.x + threadIdx.x;
    if (t >= NN * 16u) return;
    unsigned n = t >> 4, g = t & 15u;
    int start = row_ptr[n], end = row_ptr[n + 1];
    f32x4 acc = (f32x4)(0.0f);
    for (int i = start; i < end; ++i) {
        int s = col_src[i];
        u16x4 v = *reinterpret_cast<const u16x4*>(y + (size_t)s * 64 + g * 4);
#pragma unroll
        for (int j = 0; j < 4; ++j) acc[j] += b2f(v[j]);
    }
    f32x4 b4 = *reinterpret_cast<const f32x4*>(bias + g * 4);
    float ndv = nd[n];
    f32x4 o;
#pragma unroll
    for (int j = 0; j < 4; ++j) {
        float v = acc[j] * ndv + b4[j];
        o[j] = 1.0f / (1.0f + expf(-v));
    }
    *reinterpret_cast<f32x4*>(out + (size_t)n * 64 + g * 4) = o;
}

// ================= launch =================

extern "C" void kernel_launch(void* const* d_in, const int* in_sizes, int n_in,
                              void* d_out, int out_size, void* d_ws, size_t ws_size,
                              hipStream_t stream) {
    const float* x    = (const float*)d_in[0];
    const int*   esrc = (const int*)d_in[1];
    const int*   edst = (const int*)d_in[2];
    const float* W1   = (const float*)d_in[3];
    const float* b1   = (const float*)d_in[4];
    const float* W2   = (const float*)d_in[5];
    const float* b2   = (const float*)d_in[6];
    const float* W3   = (const float*)d_in[7];
    const float* b3   = (const float*)d_in[8];
    float* out = (float*)d_out;

    // ---- workspace carving (256B-aligned regions) ----
    char* base = (char*)d_ws;
    size_t off = 0;
    auto alloc = [&](size_t bytes) -> void* {
        void* p = base + off;
        off += (bytes + 255) & ~(size_t)255;
        return p;
    };
    // region1 (25.6 MB): scratch_dst (preproc) -> xb (bf16 [NN][128])
    //                    -> agg2b (bf16 [NN][128]) -> y3 (bf16 [NN][64])
    void* region1 = alloc((size_t)NN * 128 * 2);
    // region2 (44.8 MB): scratch_src (preproc) -> y1 (bf16 [NN][100]) -> h2b (bf16 [NN][224])
    void* region2 = alloc((size_t)NN * 224 * 2);
    // region3 (20 MB): h1s (bf16 [NN][100])
    void* region3 = alloc((size_t)NN * 100 * 2);
    float* ns       = (float*)alloc(NN * 4);
    float* nd       = (float*)alloc(NN * 4);
    int*   cnt_dst  = (int*)alloc(NN * 4);
    int*   row_ptr  = (int*)alloc((NN + 1) * 4);
    int*   col_src  = (int*)alloc((size_t)NE * 4);
    int*   partials = (int*)alloc(512 * 4);
    unsigned short* W1f = (unsigned short*)alloc(4 * 7 * 512 * 2);    // K=128,N=112
    unsigned short* W2f = (unsigned short*)alloc(4 * 14 * 512 * 2);   // K=128,N=224
    unsigned short* W3f = (unsigned short*)alloc(7 * 4 * 512 * 2);    // K=224,N=64
    float* b2p = (float*)alloc(224 * 4);

    int* scratch_dst      = (int*)region1;   // 16*64*6250*4 = 25.6 MB, exact fit
    unsigned short* xb    = (unsigned short*)region1;
    unsigned short* agg2b = (unsigned short*)region1;
    unsigned short* y3    = (unsigned short*)region1;
    int* scratch_src      = (int*)region2;   // 25.6 MB of 44.8
    unsigned short* y1    = (unsigned short*)region2;
    unsigned short* h2b   = (unsigned short*)region2;
    unsigned short* h1s   = (unsigned short*)region3;

    const int BLK = 256;
    const int GEMM_GRID = (NN / 16 + 3) / 4;   // 6250 waves / 4 per block = 1563

    // ---- graph preprocessing (no global atomics; 1024-block grids) ----
    partial_hist_kernel<<<NBUCK * CHUNKS, 256, 0, stream>>>(esrc, edst, scratch_src, scratch_dst);
    reduce_hist_kernel<<<grid_for(NN, BLK), BLK, 0, stream>>>(scratch_src, scratch_dst,
                                                              ns, nd, cnt_dst);
    block_sum_kernel<<<NB_SCAN, SCAN_BLK, 0, stream>>>(cnt_dst, partials);
    scan_partials_kernel<<<1, 512, 0, stream>>>(partials);
    block_scan_kernel<<<NB_SCAN, SCAN_BLK, 0, stream>>>(cnt_dst, partials, row_ptr);
    chunk_offs_kernel<<<grid_for(NN, BLK), BLK, 0, stream>>>(scratch_dst, row_ptr);
    fill_chunked_kernel<<<NBUCK * CHUNKS, 256, 0, stream>>>(esrc, edst, scratch_dst, col_src);

    // ---- bf16 prep (xb overwrites scratch_dst AFTER fill completes) ----
    f32_to_bf16_kernel<<<grid_for((long)NN * 128 / 4, BLK, 1 << 30), BLK, 0, stream>>>(
        x, xb, NN * 128 / 4);
    repack_kernel<128, 100, 7><<<grid_for(28 * 512, BLK), BLK, 0, stream>>>(W1, W1f, 28 * 512);
    repack_kernel<100, 200, 14><<<grid_for(56 * 512, BLK), BLK, 0, stream>>>(W2, W2f, 56 * 512);
    repack_kernel<200, 64, 4><<<grid_for(28 * 512, BLK), BLK, 0, stream>>>(W3, W3f, 28 * 512);
    padbias_kernel<<<1, 256, 0, stream>>>(b2, b2p, 200, 224);

    // ---- L1: y1 = (x @ W1) * ns  (bf16 [NN][100]) ----  (y1 overwrites scratch_src; OK)
    gemm_kernel<4, 7, 100, 2, 128><<<GEMM_GRID, BLK, 0, stream>>>(xb, W1f, ns, nullptr, y1);
    // h1s = elu(gather(y1)*nd + b1) * ns  (bf16 [NN][100])
    gather1_kernel<<<grid_for((long)NN * 25, BLK, 1 << 30), BLK, 0, stream>>>(
        y1, row_ptr, col_src, ns, nd, b1, h1s);

    // ---- L2: agg2 = gather(h1s)  (bf16 [NN][128], zero-padded) ----
    hipMemsetAsync(agg2b, 0, (size_t)NN * 128 * 2, stream);
    gather2_kernel<<<grid_for((long)NN * 25, BLK, 1 << 30), BLK, 0, stream>>>(
        h1s, row_ptr, col_src, agg2b);
    // h2 = elu((agg2 @ W2)*nd + b2)  (bf16 [NN][224], pads auto-zero)
    gemm_kernel<4, 14, 200, 1, 128><<<GEMM_GRID, BLK, 0, stream>>>(agg2b, W2f, nd, b2p, h2b);

    // ---- L3: y3 = (h2 @ W3) * ns  (bf16 [NN][64]) ----
    gemm_kernel<7, 4, 64, 2, 224><<<GEMM_GRID, BLK, 0, stream>>>(h2b, W3f, ns, nullptr, y3);
    // out = sigmoid(gather(y3)*nd + b3)
    gather3_kernel<<<grid_for((long)NN * 16, BLK, 1 << 30), BLK, 0, stream>>>(
        y3, row_ptr, col_src, nd, b3, out);
}

// Round 10
// 416.446 us; speedup vs baseline: 1.5347x; 1.2582x over previous
//
#include <hip/hip_runtime.h>
#include <hip/hip_bf16.h>
#include <math.h>

#define NN 100000
#define NE 1600000

#define NBUCK 8
#define BSZ (NN / NBUCK)       // 12500
#define CHUNKS 64
#define CH_E (NE / CHUNKS)     // 25000

#define SCAN_BLK 256
#define NB_SCAN ((NN + SCAN_BLK - 1) / SCAN_BLK)   // 391

typedef float f32x4 __attribute__((ext_vector_type(4)));
typedef short s16x8 __attribute__((ext_vector_type(8)));
typedef unsigned short u16x4 __attribute__((ext_vector_type(4)));
typedef int i32x4 __attribute__((ext_vector_type(4)));

static inline int grid_for(long total, int block, long cap = 16384) {
    long b = (total + block - 1) / block;
    if (b > cap) b = cap;
    if (b < 1) b = 1;
    return (int)b;
}

__device__ __forceinline__ unsigned short f2b(float f) {
    __hip_bfloat16 h = __float2bfloat16(f);   // round-to-nearest
    return __builtin_bit_cast(unsigned short, h);
}
__device__ __forceinline__ float b2f(unsigned short u) {
    unsigned int x = ((unsigned int)u) << 16;
    return __builtin_bit_cast(float, x);
}

// ================= graph preprocessing (no global atomics) =================
// Packed LDS histogram: src count in lo 16 bits, dst count in hi 16 bits.
// Per-chunk counts <= CH_E = 25000 < 2^15 -> no cross-carry possible.

__global__ __launch_bounds__(256) void partial_hist_kernel(
    const int* __restrict__ src, const int* __restrict__ dst,
    int* __restrict__ scratch)
{
    __shared__ int h[BSZ];   // 50 KB
    int g = blockIdx.x & 7, c = blockIdx.x >> 3;
    int lo = g * BSZ;
    for (int i = threadIdx.x; i < BSZ; i += 256) h[i] = 0;
    __syncthreads();
    const i32x4* src4 = reinterpret_cast<const i32x4*>(src + c * CH_E);
    const i32x4* dst4 = reinterpret_cast<const i32x4*>(dst + c * CH_E);
    for (int i = threadIdx.x; i < CH_E / 4; i += 256) {
        i32x4 s4 = src4[i];
        i32x4 d4 = dst4[i];
#pragma unroll
        for (int j = 0; j < 4; ++j) {
            unsigned si = (unsigned)(s4[j] - lo);
            unsigned di = (unsigned)(d4[j] - lo);
            if (si < BSZ) atomicAdd(&h[si], 1);
            if (di < BSZ) atomicAdd(&h[di], 0x10000);
        }
    }
    __syncthreads();
    int* o = scratch + ((size_t)g * CHUNKS + c) * BSZ;
    for (int i = threadIdx.x; i < BSZ; i += 256) o[i] = h[i];
}

// Sum chunk-partials per node -> norms (fused) + cnt_dst for the scan.
__global__ void reduce_hist_kernel(const int* __restrict__ scratch,
                                   float* __restrict__ ns, float* __restrict__ nd,
                                   int* __restrict__ cnt_dst) {
    int n = blockIdx.x * blockDim.x + threadIdx.x;
    if (n >= NN) return;
    int g = n / BSZ, i = n - g * BSZ;
    const int* p = scratch + (size_t)g * CHUNKS * BSZ + i;
    unsigned cs = 0, cd = 0;
#pragma unroll 8
    for (int c = 0; c < CHUNKS; ++c) {
        unsigned v = (unsigned)p[(size_t)c * BSZ];
        cs += v & 0xffffu;
        cd += v >> 16;
    }
    ns[n] = rsqrtf(fmaxf((float)cs, 1.0f));
    nd[n] = rsqrtf(fmaxf((float)cd, 1.0f));
    cnt_dst[n] = (int)cd;
}

__global__ void block_sum_kernel(const int* __restrict__ cnt, int* __restrict__ partials) {
    __shared__ int sm[SCAN_BLK];
    int i = blockIdx.x * SCAN_BLK + threadIdx.x;
    sm[threadIdx.x] = (i < NN) ? cnt[i] : 0;
    __syncthreads();
    for (int s = SCAN_BLK / 2; s > 0; s >>= 1) {
        if (threadIdx.x < s) sm[threadIdx.x] += sm[threadIdx.x + s];
        __syncthreads();
    }
    if (threadIdx.x == 0) partials[blockIdx.x] = sm[0];
}

__global__ void scan_partials_kernel(int* __restrict__ p) {
    __shared__ int sm[512];
    int tid = threadIdx.x;
    int v = (tid < NB_SCAN) ? p[tid] : 0;
    sm[tid] = v;
    __syncthreads();
    for (int off = 1; off < 512; off <<= 1) {
        int t = (tid >= off) ? sm[tid - off] : 0;
        __syncthreads();
        sm[tid] += t;
        __syncthreads();
    }
    if (tid < NB_SCAN) p[tid] = sm[tid] - v;   // exclusive
}

__global__ void block_scan_kernel(const int* __restrict__ cnt, const int* __restrict__ partials,
                                  int* __restrict__ row_ptr) {
    __shared__ int sm[SCAN_BLK];
    int i = blockIdx.x * SCAN_BLK + threadIdx.x;
    int v = (i < NN) ? cnt[i] : 0;
    sm[threadIdx.x] = v;
    __syncthreads();
    for (int off = 1; off < SCAN_BLK; off <<= 1) {
        int t = (threadIdx.x >= off) ? sm[threadIdx.x - off] : 0;
        __syncthreads();
        sm[threadIdx.x] += t;
        __syncthreads();
    }
    if (i < NN) {
        int excl = partials[blockIdx.x] + sm[threadIdx.x] - v;
        row_ptr[i] = excl;
        if (i == NN - 1) row_ptr[NN] = excl + v;
    }
}

// Turn dst chunk-partials (hi halves) into per-(node,chunk) start offsets (in place).
__global__ void chunk_offs_kernel(int* __restrict__ scratch, const int* __restrict__ row_ptr) {
    int n = blockIdx.x * blockDim.x + threadIdx.x;
    if (n >= NN) return;
    int g = n / BSZ, i = n - g * BSZ;
    int* pd = scratch + (size_t)g * CHUNKS * BSZ + i;
    int base = row_ptr[n];
#pragma unroll 8
    for (int c = 0; c < CHUNKS; ++c) {
        unsigned cnt = ((unsigned)pd[(size_t)c * BSZ]) >> 16;
        pd[(size_t)c * BSZ] = base;
        base += (int)cnt;
    }
}

// Atomic-free-in-global CSR fill: block (g,c) loads its bucket/chunk offsets to
// LDS, places edges via LDS atomics, writes col_src to disjoint regions.
__global__ __launch_bounds__(256) void fill_chunked_kernel(
    const int* __restrict__ src, const int* __restrict__ dst,
    const int* __restrict__ scratch, int* __restrict__ col_src)
{
    __shared__ int off[BSZ];   // 50 KB
    int g = blockIdx.x & 7, c = blockIdx.x >> 3;
    int lo = g * BSZ;
    const int* pd = scratch + ((size_t)g * CHUNKS + c) * BSZ;
    for (int i = threadIdx.x; i < BSZ; i += 256) off[i] = pd[i];
    __syncthreads();
    const i32x4* src4 = reinterpret_cast<const i32x4*>(src + c * CH_E);
    const i32x4* dst4 = reinterpret_cast<const i32x4*>(dst + c * CH_E);
    for (int i = threadIdx.x; i < CH_E / 4; i += 256) {
        i32x4 s4 = src4[i];
        i32x4 d4 = dst4[i];
#pragma unroll
        for (int j = 0; j < 4; ++j) {
            unsigned di = (unsigned)(d4[j] - lo);
            if (di < BSZ) {
                int p = atomicAdd(&off[di], 1);
                col_src[p] = s4[j];
            }
        }
    }
}

// ================= weight prep =================

// W [K_REAL][N_REAL] f32 -> fragment-packed bf16 (zero-padded).
// Wf[frag*512 + lane*8 + j] = W[kt*32 + (lane>>4)*8 + j][nt*16 + (lane&15)]
template <int K_REAL, int N_REAL, int NTILES>
__global__ void repack_kernel(const float* __restrict__ W, unsigned short* __restrict__ Wf,
                              int total) {
    int t = blockIdx.x * blockDim.x + threadIdx.x;
    if (t >= total) return;
    int j = t & 7, lane = (t >> 3) & 63, frag = t >> 9;
    int kt = frag / NTILES, nt = frag - kt * NTILES;
    int k = kt * 32 + (lane >> 4) * 8 + j;
    int n = nt * 16 + (lane & 15);
    float v = (k < K_REAL && n < N_REAL) ? W[(size_t)k * N_REAL + n] : 0.0f;
    Wf[t] = f2b(v);
}

__global__ void padbias_kernel(const float* __restrict__ b, float* __restrict__ bp,
                               int nreal, int npad) {
    int t = blockIdx.x * blockDim.x + threadIdx.x;
    if (t < npad) bp[t] = (t < nreal) ? b[t] : 0.0f;
}

// ================= MFMA GEMM =================
// AMODE 0: A is bf16 [NN][K_PAD].  AMODE 1: A is f32 [NN][K_PAD], converted in-register.
// EPI 1: bf16 out[row*(NTILES*16) + col] = elu(acc * rowscale[row] + bias[col])
// EPI 2: bf16 out[row*N_REAL + col]     = acc * rowscale[row]   (col < N_REAL only)
template <int K_STEPS, int NTILES, int N_REAL, int EPI, int K_PAD, int AMODE>
__global__ __launch_bounds__(256) void gemm_kernel(
    const void* __restrict__ Aptr, const unsigned short* __restrict__ Wf,
    const float* __restrict__ rowscale, const float* __restrict__ bias,
    void* __restrict__ outv)
{
    int wave = blockIdx.x * (blockDim.x >> 6) + (threadIdx.x >> 6);
    int row0 = wave << 4;
    if (row0 >= NN) return;
    int lane = threadIdx.x & 63;
    int r = lane & 15, half = lane >> 4;

    f32x4 acc[NTILES];
#pragma unroll
    for (int nt = 0; nt < NTILES; ++nt) acc[nt] = (f32x4)(0.0f);

#pragma unroll
    for (int kt = 0; kt < K_STEPS; ++kt) {
        s16x8 a;
        if (AMODE == 0) {
            const unsigned short* arow = (const unsigned short*)Aptr
                + (size_t)(row0 + r) * K_PAD + half * 8 + kt * 32;
            a = *reinterpret_cast<const s16x8*>(arow);
        } else {
            const float* arow = (const float*)Aptr
                + (size_t)(row0 + r) * K_PAD + half * 8 + kt * 32;
            f32x4 alo = *reinterpret_cast<const f32x4*>(arow);
            f32x4 ahi = *reinterpret_cast<const f32x4*>(arow + 4);
#pragma unroll
            for (int j = 0; j < 4; ++j) {
                a[j]     = (short)f2b(alo[j]);
                a[4 + j] = (short)f2b(ahi[j]);
            }
        }
#pragma unroll
        for (int nt = 0; nt < NTILES; ++nt) {
            s16x8 b = *reinterpret_cast<const s16x8*>(
                Wf + (((kt * NTILES + nt) << 9) | (lane << 3)));
            acc[nt] = __builtin_amdgcn_mfma_f32_16x16x32_bf16(a, b, acc[nt], 0, 0, 0);
        }
    }

    int colbase = lane & 15;
    float rs[4];
#pragma unroll
    for (int j = 0; j < 4; ++j) rs[j] = rowscale[row0 + half * 4 + j];

    if (EPI == 2) {
        unsigned short* out = (unsigned short*)outv;
#pragma unroll
        for (int nt = 0; nt < NTILES; ++nt) {
            int col = nt * 16 + colbase;
            if (col < N_REAL) {
#pragma unroll
                for (int j = 0; j < 4; ++j) {
                    int row = row0 + half * 4 + j;
                    out[(size_t)row * N_REAL + col] = f2b(acc[nt][j] * rs[j]);
                }
            }
        }
    } else {
        unsigned short* out = (unsigned short*)outv;
        const int NOUT = NTILES * 16;
#pragma unroll
        for (int nt = 0; nt < NTILES; ++nt) {
            int col = nt * 16 + colbase;
            float bv = bias[col];
#pragma unroll
            for (int j = 0; j < 4; ++j) {
                int row = row0 + half * 4 + j;
                float v = acc[nt][j] * rs[j] + bv;
                v = (v > 0.0f) ? v : expm1f(v);
                out[(size_t)row * NOUT + col] = f2b(v);
            }
        }
    }
}

// ================= gathers (4-way unrolled for MLP) =================

#define GACC4(yb, stride)                                                        \
    int i = start;                                                               \
    f32x4 a0 = (f32x4)(0.0f), a1 = (f32x4)(0.0f), a2 = (f32x4)(0.0f),            \
          a3 = (f32x4)(0.0f);                                                    \
    for (; i + 4 <= end; i += 4) {                                               \
        int s0 = col_src[i], s1 = col_src[i + 1];                                \
        int s2 = col_src[i + 2], s3 = col_src[i + 3];                            \
        u16x4 v0 = *reinterpret_cast<const u16x4*>(yb + (size_t)s0 * stride + g * 4); \
        u16x4 v1 = *reinterpret_cast<const u16x4*>(yb + (size_t)s1 * stride + g * 4); \
        u16x4 v2 = *reinterpret_cast<const u16x4*>(yb + (size_t)s2 * stride + g * 4); \
        u16x4 v3 = *reinterpret_cast<const u16x4*>(yb + (size_t)s3 * stride + g * 4); \
        _Pragma("unroll")                                                        \
        for (int j = 0; j < 4; ++j) {                                            \
            a0[j] += b2f(v0[j]); a1[j] += b2f(v1[j]);                            \
            a2[j] += b2f(v2[j]); a3[j] += b2f(v3[j]);                            \
        }                                                                        \
    }                                                                            \
    for (; i < end; ++i) {                                                       \
        int s0 = col_src[i];                                                     \
        u16x4 v0 = *reinterpret_cast<const u16x4*>(yb + (size_t)s0 * stride + g * 4); \
        _Pragma("unroll")                                                        \
        for (int j = 0; j < 4; ++j) a0[j] += b2f(v0[j]);                         \
    }                                                                            \
    f32x4 acc;                                                                   \
    _Pragma("unroll")                                                            \
    for (int j = 0; j < 4; ++j) acc[j] = (a0[j] + a1[j]) + (a2[j] + a3[j]);

// gather1: y1 bf16 [NN][100] -> h1s bf16 [NN][100];  h1s = elu(sum*nd + b1) * ns
__global__ void gather1_kernel(const unsigned short* __restrict__ y, const int* __restrict__ row_ptr,
                               const int* __restrict__ col_src, const float* __restrict__ ns,
                               const float* __restrict__ nd, const float* __restrict__ bias,
                               unsigned short* __restrict__ out) {
    unsigned t = blockIdx.x * blockDim.x + threadIdx.x;
    if (t >= NN * 25u) return;
    unsigned n = t / 25u, g = t - n * 25u;
    int start = row_ptr[n], end = row_ptr[n + 1];
    GACC4(y, 100)
    f32x4 b4 = *reinterpret_cast<const f32x4*>(bias + g * 4);
    float ndv = nd[n], nsv = ns[n];
    u16x4 o;
#pragma unroll
    for (int j = 0; j < 4; ++j) {
        float v = acc[j] * ndv + b4[j];
        v = (v > 0.0f) ? v : expm1f(v);
        o[j] = f2b(v * nsv);
    }
    *reinterpret_cast<u16x4*>(out + (size_t)n * 100 + g * 4) = o;
}

// gather2: h1s bf16 [NN][100] -> agg2b bf16 [NN][128] (raw sums cols 0..99;
// groups 25..31 write the zero pad -> no separate memset needed)
__global__ void gather2_kernel(const unsigned short* __restrict__ y, const int* __restrict__ row_ptr,
                               const int* __restrict__ col_src, unsigned short* __restrict__ out) {
    unsigned t = blockIdx.x * blockDim.x + threadIdx.x;
    if (t >= NN * 32u) return;
    unsigned n = t >> 5, g = t & 31u;
    if (g >= 25u) {
        u16x4 z = (u16x4)(0);
        *reinterpret_cast<u16x4*>(out + (size_t)n * 128 + 100 + (g - 25u) * 4) = z;
        return;
    }
    int start = row_ptr[n], end = row_ptr[n + 1];
    GACC4(y, 100)
    u16x4 o;
#pragma unroll
    for (int j = 0; j < 4; ++j) o[j] = f2b(acc[j]);
    *reinterpret_cast<u16x4*>(out + (size_t)n * 128 + g * 4) = o;
}

// gather3: y3 bf16 [NN][64] -> out f32 [NN][64];  out = sigmoid(sum*nd + b3)
__global__ void gather3_kernel(const unsigned short* __restrict__ y, const int* __restrict__ row_ptr,
                               const int* __restrict__ col_src, const float* __restrict__ nd,
                               const float* __restrict__ bias, float* __restrict__ out) {
    unsigned t = blockIdx.x * blockDim.x + threadIdx.x;
    if (t >= NN * 16u) return;
    unsigned n = t >> 4, g = t & 15u;
    int start = row_ptr[n], end = row_ptr[n + 1];
    GACC4(y, 64)
    f32x4 b4 = *reinterpret_cast<const f32x4*>(bias + g * 4);
    float ndv = nd[n];
    f32x4 o;
#pragma unroll
    for (int j = 0; j < 4; ++j) {
        float v = acc[j] * ndv + b4[j];
        o[j] = 1.0f / (1.0f + expf(-v));
    }
    *reinterpret_cast<f32x4*>(out + (size_t)n * 64 + g * 4) = o;
}

// ================= launch =================

extern "C" void kernel_launch(void* const* d_in, const int* in_sizes, int n_in,
                              void* d_out, int out_size, void* d_ws, size_t ws_size,
                              hipStream_t stream) {
    const float* x    = (const float*)d_in[0];
    const int*   esrc = (const int*)d_in[1];
    const int*   edst = (const int*)d_in[2];
    const float* W1   = (const float*)d_in[3];
    const float* b1   = (const float*)d_in[4];
    const float* W2   = (const float*)d_in[5];
    const float* b2   = (const float*)d_in[6];
    const float* W3   = (const float*)d_in[7];
    const float* b3   = (const float*)d_in[8];
    float* out = (float*)d_out;

    // ---- workspace carving (256B-aligned regions) ----
    char* base = (char*)d_ws;
    size_t off = 0;
    auto alloc = [&](size_t bytes) -> void* {
        void* p = base + off;
        off += (bytes + 255) & ~(size_t)255;
        return p;
    };
    // region1 (25.6 MB): scratch (packed hist -> offsets, preproc)
    //                    -> agg2b (bf16 [NN][128]) -> y3 (bf16 [NN][64])
    void* region1 = alloc((size_t)NN * 128 * 2);
    // region2 (44.8 MB): y1 (bf16 [NN][100]) -> h2b (bf16 [NN][224])
    void* region2 = alloc((size_t)NN * 224 * 2);
    // region3 (20 MB): h1s (bf16 [NN][100])
    void* region3 = alloc((size_t)NN * 100 * 2);
    float* ns       = (float*)alloc(NN * 4);
    float* nd       = (float*)alloc(NN * 4);
    int*   cnt_dst  = (int*)alloc(NN * 4);
    int*   row_ptr  = (int*)alloc((NN + 1) * 4);
    int*   col_src  = (int*)alloc((size_t)NE * 4);
    int*   partials = (int*)alloc(512 * 4);
    unsigned short* W1f = (unsigned short*)alloc(4 * 7 * 512 * 2);    // K=128,N=112
    unsigned short* W2f = (unsigned short*)alloc(4 * 14 * 512 * 2);   // K=128,N=224
    unsigned short* W3f = (unsigned short*)alloc(7 * 4 * 512 * 2);    // K=224,N=64
    float* b2p = (float*)alloc(224 * 4);

    int* scratch          = (int*)region1;   // 8*64*12500*4 = 25.6 MB, exact fit
    unsigned short* agg2b = (unsigned short*)region1;
    unsigned short* y3    = (unsigned short*)region1;
    unsigned short* y1    = (unsigned short*)region2;
    unsigned short* h2b   = (unsigned short*)region2;
    unsigned short* h1s   = (unsigned short*)region3;

    const int BLK = 256;
    const int GEMM_GRID = (NN / 16 + 3) / 4;   // 6250 waves / 4 per block = 1563

    // ---- graph preprocessing (no global atomics; packed 512-block hist) ----
    partial_hist_kernel<<<NBUCK * CHUNKS, 256, 0, stream>>>(esrc, edst, scratch);
    reduce_hist_kernel<<<grid_for(NN, BLK), BLK, 0, stream>>>(scratch, ns, nd, cnt_dst);
    block_sum_kernel<<<NB_SCAN, SCAN_BLK, 0, stream>>>(cnt_dst, partials);
    scan_partials_kernel<<<1, 512, 0, stream>>>(partials);
    block_scan_kernel<<<NB_SCAN, SCAN_BLK, 0, stream>>>(cnt_dst, partials, row_ptr);
    chunk_offs_kernel<<<grid_for(NN, BLK), BLK, 0, stream>>>(scratch, row_ptr);
    fill_chunked_kernel<<<NBUCK * CHUNKS, 256, 0, stream>>>(esrc, edst, scratch, col_src);

    // ---- weight prep ----
    repack_kernel<128, 100, 7><<<grid_for(28 * 512, BLK), BLK, 0, stream>>>(W1, W1f, 28 * 512);
    repack_kernel<100, 200, 14><<<grid_for(56 * 512, BLK), BLK, 0, stream>>>(W2, W2f, 56 * 512);
    repack_kernel<200, 64, 4><<<grid_for(28 * 512, BLK), BLK, 0, stream>>>(W3, W3f, 28 * 512);
    padbias_kernel<<<1, 256, 0, stream>>>(b2, b2p, 200, 224);

    // ---- L1: y1 = (x @ W1) * ns  (bf16 [NN][100]); A read as f32 directly ----
    gemm_kernel<4, 7, 100, 2, 128, 1><<<GEMM_GRID, BLK, 0, stream>>>(x, W1f, ns, nullptr, y1);
    // h1s = elu(gather(y1)*nd + b1) * ns  (bf16 [NN][100])
    gather1_kernel<<<grid_for((long)NN * 25, BLK, 1 << 30), BLK, 0, stream>>>(
        y1, row_ptr, col_src, ns, nd, b1, h1s);

    // ---- L2: agg2 = gather(h1s)  (bf16 [NN][128], pad written by kernel) ----
    gather2_kernel<<<grid_for((long)NN * 32, BLK, 1 << 30), BLK, 0, stream>>>(
        h1s, row_ptr, col_src, agg2b);
    // h2 = elu((agg2 @ W2)*nd + b2)  (bf16 [NN][224], pads auto-zero)
    gemm_kernel<4, 14, 200, 1, 128, 0><<<GEMM_GRID, BLK, 0, stream>>>(agg2b, W2f, nd, b2p, h2b);

    // ---- L3: y3 = (h2 @ W3) * ns  (bf16 [NN][64]) ----
    gemm_kernel<7, 4, 64, 2, 224, 0><<<GEMM_GRID, BLK, 0, stream>>>(h2b, W3f, ns, nullptr, y3);
    // out = sigmoid(gather(y3)*nd + b3)
    gather3_kernel<<<grid_for((long)NN * 16, BLK, 1 << 30), BLK, 0, stream>>>(
        y3, row_ptr, col_src, nd, b3, out);
}

// Round 11
// 399.692 us; speedup vs baseline: 1.5990x; 1.0419x over previous
//
#include <hip/hip_runtime.h>
#include <hip/hip_bf16.h>
#include <math.h>

#define NN 100000
#define NE 1600000

#define NBUCK 8
#define BSZ (NN / NBUCK)       // 12500
#define CHUNKS 64
#define CH_E (NE / CHUNKS)     // 25000
#define FILL_BLOCKS (NBUCK * CHUNKS)   // 512
#define GEMM_GRID ((NN / 16 + 3) / 4)  // 1563

#define SCAN_BLK 256
#define NB_SCAN ((NN + SCAN_BLK - 1) / SCAN_BLK)   // 391

typedef float f32x4 __attribute__((ext_vector_type(4)));
typedef short s16x8 __attribute__((ext_vector_type(8)));
typedef unsigned short u16x4 __attribute__((ext_vector_type(4)));
typedef int i32x4 __attribute__((ext_vector_type(4)));

static inline int grid_for(long total, int block, long cap = 16384) {
    long b = (total + block - 1) / block;
    if (b > cap) b = cap;
    if (b < 1) b = 1;
    return (int)b;
}

__device__ __forceinline__ unsigned short f2b(float f) {
    __hip_bfloat16 h = __float2bfloat16(f);   // round-to-nearest
    return __builtin_bit_cast(unsigned short, h);
}
__device__ __forceinline__ float b2f(unsigned short u) {
    unsigned int x = ((unsigned int)u) << 16;
    return __builtin_bit_cast(float, x);
}

// ================= graph preprocessing (no global atomics) =================
// Packed LDS histogram: src count in lo 16 bits, dst count in hi 16 bits.
// Per-chunk counts <= CH_E = 25000 < 2^15 -> no cross-carry possible.

__global__ __launch_bounds__(256) void partial_hist_kernel(
    const int* __restrict__ src, const int* __restrict__ dst,
    int* __restrict__ scratch)
{
    __shared__ int h[BSZ];   // 50 KB
    int g = blockIdx.x & 7, c = blockIdx.x >> 3;
    int lo = g * BSZ;
    for (int i = threadIdx.x; i < BSZ; i += 256) h[i] = 0;
    __syncthreads();
    const i32x4* src4 = reinterpret_cast<const i32x4*>(src + c * CH_E);
    const i32x4* dst4 = reinterpret_cast<const i32x4*>(dst + c * CH_E);
    for (int i = threadIdx.x; i < CH_E / 4; i += 256) {
        i32x4 s4 = src4[i];
        i32x4 d4 = dst4[i];
#pragma unroll
        for (int j = 0; j < 4; ++j) {
            unsigned si = (unsigned)(s4[j] - lo);
            unsigned di = (unsigned)(d4[j] - lo);
            if (si < BSZ) atomicAdd(&h[si], 1);
            if (di < BSZ) atomicAdd(&h[di], 0x10000);
        }
    }
    __syncthreads();
    int* o = scratch + ((size_t)g * CHUNKS + c) * BSZ;
    for (int i = threadIdx.x; i < BSZ; i += 256) o[i] = h[i];
}

// Sum chunk-partials per node -> norms (fused) + cnt_dst for the scan.
__global__ void reduce_hist_kernel(const int* __restrict__ scratch,
                                   float* __restrict__ ns, float* __restrict__ nd,
                                   int* __restrict__ cnt_dst) {
    int n = blockIdx.x * blockDim.x + threadIdx.x;
    if (n >= NN) return;
    int g = n / BSZ, i = n - g * BSZ;
    const int* p = scratch + (size_t)g * CHUNKS * BSZ + i;
    unsigned cs = 0, cd = 0;
#pragma unroll 8
    for (int c = 0; c < CHUNKS; ++c) {
        unsigned v = (unsigned)p[(size_t)c * BSZ];
        cs += v & 0xffffu;
        cd += v >> 16;
    }
    ns[n] = rsqrtf(fmaxf((float)cs, 1.0f));
    nd[n] = rsqrtf(fmaxf((float)cd, 1.0f));
    cnt_dst[n] = (int)cd;
}

__global__ void block_sum_kernel(const int* __restrict__ cnt, int* __restrict__ partials) {
    __shared__ int sm[SCAN_BLK];
    int i = blockIdx.x * SCAN_BLK + threadIdx.x;
    sm[threadIdx.x] = (i < NN) ? cnt[i] : 0;
    __syncthreads();
    for (int s = SCAN_BLK / 2; s > 0; s >>= 1) {
        if (threadIdx.x < s) sm[threadIdx.x] += sm[threadIdx.x + s];
        __syncthreads();
    }
    if (threadIdx.x == 0) partials[blockIdx.x] = sm[0];
}

__global__ void scan_partials_kernel(int* __restrict__ p) {
    __shared__ int sm[512];
    int tid = threadIdx.x;
    int v = (tid < NB_SCAN) ? p[tid] : 0;
    sm[tid] = v;
    __syncthreads();
    for (int off = 1; off < 512; off <<= 1) {
        int t = (tid >= off) ? sm[tid - off] : 0;
        __syncthreads();
        sm[tid] += t;
        __syncthreads();
    }
    if (tid < NB_SCAN) p[tid] = sm[tid] - v;   // exclusive
}

__global__ void block_scan_kernel(const int* __restrict__ cnt, const int* __restrict__ partials,
                                  int* __restrict__ row_ptr) {
    __shared__ int sm[SCAN_BLK];
    int i = blockIdx.x * SCAN_BLK + threadIdx.x;
    int v = (i < NN) ? cnt[i] : 0;
    sm[threadIdx.x] = v;
    __syncthreads();
    for (int off = 1; off < SCAN_BLK; off <<= 1) {
        int t = (threadIdx.x >= off) ? sm[threadIdx.x - off] : 0;
        __syncthreads();
        sm[threadIdx.x] += t;
        __syncthreads();
    }
    if (i < NN) {
        int excl = partials[blockIdx.x] + sm[threadIdx.x] - v;
        row_ptr[i] = excl;
        if (i == NN - 1) row_ptr[NN] = excl + v;
    }
}

// Turn dst chunk-partials (hi halves) into per-(node,chunk) start offsets (in place).
__global__ void chunk_offs_kernel(int* __restrict__ scratch, const int* __restrict__ row_ptr) {
    int n = blockIdx.x * blockDim.x + threadIdx.x;
    if (n >= NN) return;
    int g = n / BSZ, i = n - g * BSZ;
    int* pd = scratch + (size_t)g * CHUNKS * BSZ + i;
    int base = row_ptr[n];
#pragma unroll 8
    for (int c = 0; c < CHUNKS; ++c) {
        unsigned cnt = ((unsigned)pd[(size_t)c * BSZ]) >> 16;
        pd[(size_t)c * BSZ] = base;
        base += (int)cnt;
    }
}

// ================= weight prep (all repacks + bias pad in one kernel) =================

template <int K_REAL, int N_REAL, int NTILES>
__device__ __forceinline__ void repack_one(const float* __restrict__ W,
                                           unsigned short* __restrict__ Wf, int t) {
    int j = t & 7, lane = (t >> 3) & 63, frag = t >> 9;
    int kt = frag / NTILES, nt = frag - kt * NTILES;
    int k = kt * 32 + (lane >> 4) * 8 + j;
    int n = nt * 16 + (lane & 15);
    float v = (k < K_REAL && n < N_REAL) ? W[(size_t)k * N_REAL + n] : 0.0f;
    Wf[t] = f2b(v);
}

#define R1_N (28 * 512)   // 14336
#define R2_N (56 * 512)   // 28672
#define R3_N (28 * 512)   // 14336

__global__ void prep_kernel(const float* __restrict__ W1, unsigned short* __restrict__ W1f,
                            const float* __restrict__ W2, unsigned short* __restrict__ W2f,
                            const float* __restrict__ W3, unsigned short* __restrict__ W3f,
                            const float* __restrict__ b2, float* __restrict__ b2p) {
    int t = blockIdx.x * blockDim.x + threadIdx.x;
    if (t < R1_N) {
        repack_one<128, 100, 7>(W1, W1f, t);
    } else if (t < R1_N + R2_N) {
        repack_one<100, 200, 14>(W2, W2f, t - R1_N);
    } else if (t < R1_N + R2_N + R3_N) {
        repack_one<200, 64, 4>(W3, W3f, t - R1_N - R2_N);
    } else if (t < R1_N + R2_N + R3_N + 224) {
        int i = t - R1_N - R2_N - R3_N;
        b2p[i] = (i < 200) ? b2[i] : 0.0f;
    }
}

// ================= MFMA GEMM body =================
// AMODE 0: A is bf16 [NN][K_PAD].  AMODE 1: A is f32 [NN][K_PAD], converted in-register.
// EPI 1: bf16 out[row*(NTILES*16) + col] = elu(acc * rowscale[row] + bias[col])
// EPI 2: bf16 out[row*N_REAL + col]     = acc * rowscale[row]   (col < N_REAL only)
template <int K_STEPS, int NTILES, int N_REAL, int EPI, int K_PAD, int AMODE>
__device__ __forceinline__ void gemm_body(
    int wave, int lane, const void* __restrict__ Aptr,
    const unsigned short* __restrict__ Wf, const float* __restrict__ rowscale,
    const float* __restrict__ bias, void* __restrict__ outv)
{
    int row0 = wave << 4;
    if (row0 >= NN) return;
    int r = lane & 15, half = lane >> 4;

    f32x4 acc[NTILES];
#pragma unroll
    for (int nt = 0; nt < NTILES; ++nt) acc[nt] = (f32x4)(0.0f);

#pragma unroll
    for (int kt = 0; kt < K_STEPS; ++kt) {
        s16x8 a;
        if (AMODE == 0) {
            const unsigned short* arow = (const unsigned short*)Aptr
                + (size_t)(row0 + r) * K_PAD + half * 8 + kt * 32;
            a = *reinterpret_cast<const s16x8*>(arow);
        } else {
            const float* arow = (const float*)Aptr
                + (size_t)(row0 + r) * K_PAD + half * 8 + kt * 32;
            f32x4 alo = *reinterpret_cast<const f32x4*>(arow);
            f32x4 ahi = *reinterpret_cast<const f32x4*>(arow + 4);
#pragma unroll
            for (int j = 0; j < 4; ++j) {
                a[j]     = (short)f2b(alo[j]);
                a[4 + j] = (short)f2b(ahi[j]);
            }
        }
#pragma unroll
        for (int nt = 0; nt < NTILES; ++nt) {
            s16x8 b = *reinterpret_cast<const s16x8*>(
                Wf + (((kt * NTILES + nt) << 9) | (lane << 3)));
            acc[nt] = __builtin_amdgcn_mfma_f32_16x16x32_bf16(a, b, acc[nt], 0, 0, 0);
        }
    }

    int colbase = lane & 15;
    float rs[4];
#pragma unroll
    for (int j = 0; j < 4; ++j) rs[j] = rowscale[row0 + half * 4 + j];

    if (EPI == 2) {
        unsigned short* out = (unsigned short*)outv;
#pragma unroll
        for (int nt = 0; nt < NTILES; ++nt) {
            int col = nt * 16 + colbase;
            if (col < N_REAL) {
#pragma unroll
                for (int j = 0; j < 4; ++j) {
                    int row = row0 + half * 4 + j;
                    out[(size_t)row * N_REAL + col] = f2b(acc[nt][j] * rs[j]);
                }
            }
        }
    } else {
        unsigned short* out = (unsigned short*)outv;
        const int NOUT = NTILES * 16;
#pragma unroll
        for (int nt = 0; nt < NTILES; ++nt) {
            int col = nt * 16 + colbase;
            float bv = bias[col];
#pragma unroll
            for (int j = 0; j < 4; ++j) {
                int row = row0 + half * 4 + j;
                float v = acc[nt][j] * rs[j] + bv;
                v = (v > 0.0f) ? v : expm1f(v);
                out[(size_t)row * NOUT + col] = f2b(v);
            }
        }
    }
}

template <int K_STEPS, int NTILES, int N_REAL, int EPI, int K_PAD, int AMODE>
__global__ __launch_bounds__(256) void gemm_kernel(
    const void* __restrict__ Aptr, const unsigned short* __restrict__ Wf,
    const float* __restrict__ rowscale, const float* __restrict__ bias,
    void* __restrict__ outv)
{
    int wave = blockIdx.x * (blockDim.x >> 6) + (threadIdx.x >> 6);
    gemm_body<K_STEPS, NTILES, N_REAL, EPI, K_PAD, AMODE>(
        wave, threadIdx.x & 63, Aptr, Wf, rowscale, bias, outv);
}

// ================= packed fill + gemm1 =================
// Blocks [0, FILL_BLOCKS): atomic-free CSR fill via LDS offsets.
// Blocks [FILL_BLOCKS, FILL_BLOCKS+GEMM_GRID): L1 GEMM (independent work,
// overlaps with the fill; ns is ready since reduce_hist ran earlier).
__global__ __launch_bounds__(256) void fill_gemm1_kernel(
    const int* __restrict__ src, const int* __restrict__ dst,
    const int* __restrict__ scratch, int* __restrict__ col_src,
    const float* __restrict__ x, const unsigned short* __restrict__ W1f,
    const float* __restrict__ ns, unsigned short* __restrict__ y1)
{
    __shared__ int off[BSZ];   // 50 KB (unused by gemm blocks)
    if (blockIdx.x < FILL_BLOCKS) {
        int g = blockIdx.x & 7, c = blockIdx.x >> 3;
        int lo = g * BSZ;
        const int* pd = scratch + ((size_t)g * CHUNKS + c) * BSZ;
        for (int i = threadIdx.x; i < BSZ; i += 256) off[i] = pd[i];
        __syncthreads();
        const i32x4* src4 = reinterpret_cast<const i32x4*>(src + c * CH_E);
        const i32x4* dst4 = reinterpret_cast<const i32x4*>(dst + c * CH_E);
        for (int i = threadIdx.x; i < CH_E / 4; i += 256) {
            i32x4 s4 = src4[i];
            i32x4 d4 = dst4[i];
#pragma unroll
            for (int j = 0; j < 4; ++j) {
                unsigned di = (unsigned)(d4[j] - lo);
                if (di < BSZ) {
                    int p = atomicAdd(&off[di], 1);
                    col_src[p] = s4[j];
                }
            }
        }
    } else {
        int bid = blockIdx.x - FILL_BLOCKS;
        int wave = bid * 4 + (threadIdx.x >> 6);
        gemm_body<4, 7, 100, 2, 128, 1>(wave, threadIdx.x & 63, x, W1f, ns, nullptr, y1);
    }
}

// ================= gathers (8 loads in flight, 4 accumulator chains) =================

#define GACC8(yb, stride)                                                        \
    int i = start;                                                               \
    f32x4 a0 = (f32x4)(0.0f), a1 = (f32x4)(0.0f), a2 = (f32x4)(0.0f),            \
          a3 = (f32x4)(0.0f);                                                    \
    for (; i + 8 <= end; i += 8) {                                               \
        int s0 = col_src[i],     s1 = col_src[i + 1];                            \
        int s2 = col_src[i + 2], s3 = col_src[i + 3];                            \
        int s4 = col_src[i + 4], s5 = col_src[i + 5];                            \
        int s6 = col_src[i + 6], s7 = col_src[i + 7];                            \
        u16x4 v0 = *reinterpret_cast<const u16x4*>(yb + (size_t)s0 * stride + g * 4); \
        u16x4 v1 = *reinterpret_cast<const u16x4*>(yb + (size_t)s1 * stride + g * 4); \
        u16x4 v2 = *reinterpret_cast<const u16x4*>(yb + (size_t)s2 * stride + g * 4); \
        u16x4 v3 = *reinterpret_cast<const u16x4*>(yb + (size_t)s3 * stride + g * 4); \
        u16x4 v4 = *reinterpret_cast<const u16x4*>(yb + (size_t)s4 * stride + g * 4); \
        u16x4 v5 = *reinterpret_cast<const u16x4*>(yb + (size_t)s5 * stride + g * 4); \
        u16x4 v6 = *reinterpret_cast<const u16x4*>(yb + (size_t)s6 * stride + g * 4); \
        u16x4 v7 = *reinterpret_cast<const u16x4*>(yb + (size_t)s7 * stride + g * 4); \
        _Pragma("unroll")                                                        \
        for (int j = 0; j < 4; ++j) {                                            \
            a0[j] += b2f(v0[j]) + b2f(v4[j]);                                    \
            a1[j] += b2f(v1[j]) + b2f(v5[j]);                                    \
            a2[j] += b2f(v2[j]) + b2f(v6[j]);                                    \
            a3[j] += b2f(v3[j]) + b2f(v7[j]);                                    \
        }                                                                        \
    }                                                                            \
    for (; i + 4 <= end; i += 4) {                                               \
        int s0 = col_src[i], s1 = col_src[i + 1];                                \
        int s2 = col_src[i + 2], s3 = col_src[i + 3];                            \
        u16x4 v0 = *reinterpret_cast<const u16x4*>(yb + (size_t)s0 * stride + g * 4); \
        u16x4 v1 = *reinterpret_cast<const u16x4*>(yb + (size_t)s1 * stride + g * 4); \
        u16x4 v2 = *reinterpret_cast<const u16x4*>(yb + (size_t)s2 * stride + g * 4); \
        u16x4 v3 = *reinterpret_cast<const u16x4*>(yb + (size_t)s3 * stride + g * 4); \
        _Pragma("unroll")                                                        \
        for (int j = 0; j < 4; ++j) {                                            \
            a0[j] += b2f(v0[j]); a1[j] += b2f(v1[j]);                            \
            a2[j] += b2f(v2[j]); a3[j] += b2f(v3[j]);                            \
        }                                                                        \
    }                                                                            \
    for (; i < end; ++i) {                                                       \
        int s0 = col_src[i];                                                     \
        u16x4 v0 = *reinterpret_cast<const u16x4*>(yb + (size_t)s0 * stride + g * 4); \
        _Pragma("unroll")                                                        \
        for (int j = 0; j < 4; ++j) a0[j] += b2f(v0[j]);                         \
    }                                                                            \
    f32x4 acc;                                                                   \
    _Pragma("unroll")                                                            \
    for (int j = 0; j < 4; ++j) acc[j] = (a0[j] + a1[j]) + (a2[j] + a3[j]);

// gather1: y1 bf16 [NN][100] -> h1s bf16 [NN][100];  h1s = elu(sum*nd + b1) * ns
__global__ void gather1_kernel(const unsigned short* __restrict__ y, const int* __restrict__ row_ptr,
                               const int* __restrict__ col_src, const float* __restrict__ ns,
                               const float* __restrict__ nd, const float* __restrict__ bias,
                               unsigned short* __restrict__ out) {
    unsigned t = blockIdx.x * blockDim.x + threadIdx.x;
    if (t >= NN * 25u) return;
    unsigned n = t / 25u, g = t - n * 25u;
    int start = row_ptr[n], end = row_ptr[n + 1];
    GACC8(y, 100)
    f32x4 b4 = *reinterpret_cast<const f32x4*>(bias + g * 4);
    float ndv = nd[n], nsv = ns[n];
    u16x4 o;
#pragma unroll
    for (int j = 0; j < 4; ++j) {
        float v = acc[j] * ndv + b4[j];
        v = (v > 0.0f) ? v : expm1f(v);
        o[j] = f2b(v * nsv);
    }
    *reinterpret_cast<u16x4*>(out + (size_t)n * 100 + g * 4) = o;
}

// gather2: h1s bf16 [NN][100] -> agg2b bf16 [NN][128] (raw sums cols 0..99;
// groups 25..31 write the zero pad -> no separate memset needed)
__global__ void gather2_kernel(const unsigned short* __restrict__ y, const int* __restrict__ row_ptr,
                               const int* __restrict__ col_src, unsigned short* __restrict__ out) {
    unsigned t = blockIdx.x * blockDim.x + threadIdx.x;
    if (t >= NN * 32u) return;
    unsigned n = t >> 5, g = t & 31u;
    if (g >= 25u) {
        u16x4 z = (u16x4)(0);
        *reinterpret_cast<u16x4*>(out + (size_t)n * 128 + 100 + (g - 25u) * 4) = z;
        return;
    }
    int start = row_ptr[n], end = row_ptr[n + 1];
    GACC8(y, 100)
    u16x4 o;
#pragma unroll
    for (int j = 0; j < 4; ++j) o[j] = f2b(acc[j]);
    *reinterpret_cast<u16x4*>(out + (size_t)n * 128 + g * 4) = o;
}

// gather3: y3 bf16 [NN][64] -> out f32 [NN][64];  out = sigmoid(sum*nd + b3)
__global__ void gather3_kernel(const unsigned short* __restrict__ y, const int* __restrict__ row_ptr,
                               const int* __restrict__ col_src, const float* __restrict__ nd,
                               const float* __restrict__ bias, float* __restrict__ out) {
    unsigned t = blockIdx.x * blockDim.x + threadIdx.x;
    if (t >= NN * 16u) return;
    unsigned n = t >> 4, g = t & 15u;
    int start = row_ptr[n], end = row_ptr[n + 1];
    GACC8(y, 64)
    f32x4 b4 = *reinterpret_cast<const f32x4*>(bias + g * 4);
    float ndv = nd[n];
    f32x4 o;
#pragma unroll
    for (int j = 0; j < 4; ++j) {
        float v = acc[j] * ndv + b4[j];
        o[j] = 1.0f / (1.0f + expf(-v));
    }
    *reinterpret_cast<f32x4*>(out + (size_t)n * 64 + g * 4) = o;
}

// ================= launch =================

extern "C" void kernel_launch(void* const* d_in, const int* in_sizes, int n_in,
                              void* d_out, int out_size, void* d_ws, size_t ws_size,
                              hipStream_t stream) {
    const float* x    = (const float*)d_in[0];
    const int*   esrc = (const int*)d_in[1];
    const int*   edst = (const int*)d_in[2];
    const float* W1   = (const float*)d_in[3];
    const float* b1   = (const float*)d_in[4];
    const float* W2   = (const float*)d_in[5];
    const float* b2   = (const float*)d_in[6];
    const float* W3   = (const float*)d_in[7];
    const float* b3   = (const float*)d_in[8];
    float* out = (float*)d_out;

    // ---- workspace carving (256B-aligned regions) ----
    char* base = (char*)d_ws;
    size_t off = 0;
    auto alloc = [&](size_t bytes) -> void* {
        void* p = base + off;
        off += (bytes + 255) & ~(size_t)255;
        return p;
    };
    // region1 (25.6 MB): scratch (packed hist -> offsets, preproc)
    //                    -> agg2b (bf16 [NN][128]) -> y3 (bf16 [NN][64])
    void* region1 = alloc((size_t)NN * 128 * 2);
    // region2 (44.8 MB): y1 (bf16 [NN][100]) -> h2b (bf16 [NN][224])
    void* region2 = alloc((size_t)NN * 224 * 2);
    // region3 (20 MB): h1s (bf16 [NN][100])
    void* region3 = alloc((size_t)NN * 100 * 2);
    float* ns       = (float*)alloc(NN * 4);
    float* nd       = (float*)alloc(NN * 4);
    int*   cnt_dst  = (int*)alloc(NN * 4);
    int*   row_ptr  = (int*)alloc((NN + 1) * 4);
    int*   col_src  = (int*)alloc((size_t)NE * 4);
    int*   partials = (int*)alloc(512 * 4);
    unsigned short* W1f = (unsigned short*)alloc(R1_N * 2);
    unsigned short* W2f = (unsigned short*)alloc(R2_N * 2);
    unsigned short* W3f = (unsigned short*)alloc(R3_N * 2);
    float* b2p = (float*)alloc(224 * 4);

    int* scratch          = (int*)region1;   // 8*64*12500*4 = 25.6 MB, exact fit
    unsigned short* agg2b = (unsigned short*)region1;
    unsigned short* y3    = (unsigned short*)region1;
    unsigned short* y1    = (unsigned short*)region2;
    unsigned short* h2b   = (unsigned short*)region2;
    unsigned short* h1s   = (unsigned short*)region3;

    const int BLK = 256;

    // ---- weight prep (one kernel) ----
    prep_kernel<<<grid_for(R1_N + R2_N + R3_N + 224, BLK), BLK, 0, stream>>>(
        W1, W1f, W2, W2f, W3, W3f, b2, b2p);

    // ---- graph preprocessing (no global atomics) ----
    partial_hist_kernel<<<NBUCK * CHUNKS, 256, 0, stream>>>(esrc, edst, scratch);
    reduce_hist_kernel<<<grid_for(NN, BLK), BLK, 0, stream>>>(scratch, ns, nd, cnt_dst);
    block_sum_kernel<<<NB_SCAN, SCAN_BLK, 0, stream>>>(cnt_dst, partials);
    scan_partials_kernel<<<1, 512, 0, stream>>>(partials);
    block_scan_kernel<<<NB_SCAN, SCAN_BLK, 0, stream>>>(cnt_dst, partials, row_ptr);
    chunk_offs_kernel<<<grid_for(NN, BLK), BLK, 0, stream>>>(scratch, row_ptr);

    // ---- CSR fill packed with L1 GEMM (independent; overlap in one dispatch) ----
    fill_gemm1_kernel<<<FILL_BLOCKS + GEMM_GRID, 256, 0, stream>>>(
        esrc, edst, scratch, col_src, x, W1f, ns, y1);

    // h1s = elu(gather(y1)*nd + b1) * ns  (bf16 [NN][100])
    gather1_kernel<<<grid_for((long)NN * 25, BLK, 1 << 30), BLK, 0, stream>>>(
        y1, row_ptr, col_src, ns, nd, b1, h1s);

    // ---- L2: agg2 = gather(h1s)  (bf16 [NN][128], pad written by kernel) ----
    gather2_kernel<<<grid_for((long)NN * 32, BLK, 1 << 30), BLK, 0, stream>>>(
        h1s, row_ptr, col_src, agg2b);
    // h2 = elu((agg2 @ W2)*nd + b2)  (bf16 [NN][224], pads auto-zero)
    gemm_kernel<4, 14, 200, 1, 128, 0><<<GEMM_GRID, BLK, 0, stream>>>(agg2b, W2f, nd, b2p, h2b);

    // ---- L3: y3 = (h2 @ W3) * ns  (bf16 [NN][64]) ----
    gemm_kernel<7, 4, 64, 2, 224, 0><<<GEMM_GRID, BLK, 0, stream>>>(h2b, W3f, ns, nullptr, y3);
    // out = sigmoid(gather(y3)*nd + b3)
    gather3_kernel<<<grid_for((long)NN * 16, BLK, 1 << 30), BLK, 0, stream>>>(
        y3, row_ptr, col_src, nd, b3, out);
}